// Round 9
// baseline (240.741 us; speedup 1.0000x reference)
//
#include <hip/hip_runtime.h>
#include <math.h>

#define B_  4096
#define T_  50
#define K_  32
#define D_  64
#define H_  256
#define HL_ 128
#define G4_ 512   // 4*HL

typedef __attribute__((ext_vector_type(8))) short bf16x8;
typedef __attribute__((ext_vector_type(4))) float f32x4;

__device__ __forceinline__ float fast_exp(float x){ return __expf(x); }
__device__ __forceinline__ float fast_rcp(float x){ return __builtin_amdgcn_rcpf(x); }
__device__ __forceinline__ float sigmoidf_(float x){ return fast_rcp(1.f + fast_exp(-x)); }
__device__ __forceinline__ float tanhf_(float x){ return 1.f - 2.f*fast_rcp(1.f + fast_exp(2.f*x)); }

__device__ __forceinline__ short f2bf(float f){
  union { float f; unsigned u; } v; v.f = f;
  unsigned r = v.u + 0x7FFFu + ((v.u >> 16) & 1u);   // round-to-nearest-even
  return (short)(r >> 16);
}
__device__ __forceinline__ float bf2f(short s){
  union { unsigned u; float f; } v; v.u = ((unsigned)(unsigned short)s) << 16;
  return v.f;
}

__device__ __forceinline__ float wave_reduce_sum(float v){
  #pragma unroll
  for (int off = 32; off; off >>= 1) v += __shfl_xor(v, off);
  return v;
}

// ---------------------------------------------------------------------------
// Kernel 1: per-student head — EXACT revert to the verified R0-R3 baseline
// (DNN inside, both-matrix walk). R8's split-DNN was within noise and grew
// absmax; head micro-opts are below the ±5-10us session noise floor.
// ---------------------------------------------------------------------------
#define KROW 72
#define PROW 40

__global__ __launch_bounds__(256) void head_kernel(
    const int* __restrict__ uididx, const int* __restrict__ kcodeidx,
    const int* __restrict__ kcode_len, const float* __restrict__ qidemb,
    const int* __restrict__ qid_len, const float* __restrict__ stuE,
    const float* __restrict__ knE,
    const float* __restrict__ T_W1, const float* __restrict__ T_b1,
    const float* __restrict__ T_W2, const float* __restrict__ T_b2,
    const float* __restrict__ A_W1, const float* __restrict__ A_b1,
    const float* __restrict__ A_W2, const float* __restrict__ A_b2,
    short* __restrict__ bvec, float* __restrict__ t_val, float* __restrict__ a_val)
{
  __shared__ __align__(16) short s_kemb[K_*KROW];
  __shared__ __align__(16) short s_kembT[D_*PROW];
  __shared__ __align__(16) short s_p[64*PROW];
  __shared__ float s_stu[D_];
  __shared__ float s_mast[K_];
  __shared__ float s_kmf[K_];
  __shared__ float s_mvec[D_];
  __shared__ float s_avec[D_];
  __shared__ float s_redT[4];
  __shared__ float s_redA[4];

  const int b    = blockIdx.x;
  const int tid  = threadIdx.x;
  const int lane = tid & 63;
  const int w    = tid >> 6;
  const int l15  = lane & 15;
  const int quad = lane >> 4;
  const int klen = kcode_len[b];
  const int qlen = qid_len[b];

  if (tid < D_) s_stu[tid] = stuE[uididx[b]*D_ + tid];
  #pragma unroll
  for (int i = tid; i < 512; i += 256){
    int k = i >> 4, f4 = i & 15;
    const float4 v = *(const float4*)&knE[(size_t)kcodeidx[b*K_ + k]*D_ + f4*4];
    short4 b4; b4.x = f2bf(v.x); b4.y = f2bf(v.y); b4.z = f2bf(v.z); b4.w = f2bf(v.w);
    *(short4*)&s_kemb[k*KROW + f4*4] = b4;
    int d = f4*4;
    s_kembT[(d+0)*PROW + k] = b4.x;
    s_kembT[(d+1)*PROW + k] = b4.y;
    s_kembT[(d+2)*PROW + k] = b4.z;
    s_kembT[(d+3)*PROW + k] = b4.w;
  }
  __syncthreads();

  // mastery: 8 lanes per k, bank-rotated
  {
    int k = tid >> 3, l8 = tid & 7;
    float s = 0.f;
    #pragma unroll
    for (int j = 0; j < 8; ++j){
      int d = l8 + 8*((j + k) & 7);
      s += s_stu[d] * bf2f(s_kemb[k*KROW + d]);
    }
    s += __shfl_xor(s, 1); s += __shfl_xor(s, 2); s += __shfl_xor(s, 4);
    if (l8 == 0){
      float valid = (k < klen) ? 1.f : 0.f;
      s_mast[k] = valid * sigmoidf_(s * 0.2f);
      s_kmf[k]  = valid;
    }
  }
  __syncthreads();

  if (tid < D_){
    float mv = 0.f, av = 0.f;
    #pragma unroll 4
    for (int k = 0; k < K_; ++k){
      float e = bf2f(s_kemb[k*KROW + tid]);
      mv += s_mast[k] * e;
      av += s_kmf[k]  * e;
    }
    s_mvec[tid] = mv; s_avec[tid] = av;
  }
  __syncthreads();

  // ---- attention via MFMA; q A-frags straight from global ----
  {
    const int qrow = w*16 + l15;
    bf16x8 aq[2];
    #pragma unroll
    for (int kt = 0; kt < 2; ++kt){
      if (qrow < qlen){
        const float4 v0 = *(const float4*)&qidemb[((size_t)b*T_ + qrow)*D_ + kt*32 + quad*8];
        const float4 v1 = *(const float4*)&qidemb[((size_t)b*T_ + qrow)*D_ + kt*32 + quad*8 + 4];
        aq[kt][0]=f2bf(v0.x); aq[kt][1]=f2bf(v0.y); aq[kt][2]=f2bf(v0.z); aq[kt][3]=f2bf(v0.w);
        aq[kt][4]=f2bf(v1.x); aq[kt][5]=f2bf(v1.y); aq[kt][6]=f2bf(v1.z); aq[kt][7]=f2bf(v1.w);
      } else {
        aq[kt][0]=0; aq[kt][1]=0; aq[kt][2]=0; aq[kt][3]=0;
        aq[kt][4]=0; aq[kt][5]=0; aq[kt][6]=0; aq[kt][7]=0;
      }
    }
    f32x4 zero = {0.f, 0.f, 0.f, 0.f};
    f32x4 accs[2] = {zero, zero};
    #pragma unroll
    for (int kt = 0; kt < 2; ++kt){
      #pragma unroll
      for (int nt = 0; nt < 2; ++nt){
        bf16x8 bk = *(const bf16x8*)&s_kemb[(nt*16 + l15)*KROW + kt*32 + quad*8];
        accs[nt] = __builtin_amdgcn_mfma_f32_16x16x32_bf16(aq[kt], bk, accs[nt], 0, 0, 0);
      }
    }
    #pragma unroll
    for (int r = 0; r < 4; ++r){
      float v0 = (l15      < klen) ? accs[0][r]*0.15f : -1e9f;
      float v1 = (l15 + 16 < klen) ? accs[1][r]*0.15f : -1e9f;
      float mx = fmaxf(v0, v1);
      #pragma unroll
      for (int off = 1; off < 16; off <<= 1) mx = fmaxf(mx, __shfl_xor(mx, off));
      float e0 = fast_exp(v0 - mx), e1 = fast_exp(v1 - mx);
      float sm = e0 + e1;
      #pragma unroll
      for (int off = 1; off < 16; off <<= 1) sm += __shfl_xor(sm, off);
      float inv = fast_rcp(sm);
      int row = w*16 + quad*4 + r;
      s_p[row*PROW + l15]      = f2bf(e0 * inv);
      s_p[row*PROW + 16 + l15] = f2bf(e1 * inv);
    }
    bf16x8 ap = *(const bf16x8*)&s_p[(w*16 + l15)*PROW + quad*8];
    #pragma unroll
    for (int nt = 0; nt < 4; ++nt){
      bf16x8 bv = *(const bf16x8*)&s_kembT[(nt*16 + l15)*PROW + quad*8];
      f32x4 acco = __builtin_amdgcn_mfma_f32_16x16x32_bf16(ap, bv, zero, 0, 0, 0);
      #pragma unroll
      for (int r = 0; r < 4; ++r){
        int t = w*16 + quad*4 + r;
        if (t < qlen) bvec[((size_t)b*T_ + t)*D_ + nt*16 + l15] = f2bf(acco[r]);
      }
    }
  }

  // ---- both DNNs interleaved (verified baseline form) ----
  {
    float accT = T_b1[tid];
    float accA = A_b1[tid];
    #pragma unroll 4
    for (int d = 0; d < D_; ++d){
      float mv = s_mvec[d], av = s_avec[d];
      accT += mv * T_W1[d*H_ + tid];
      accA += av * A_W1[d*H_ + tid];
    }
    float termT = tanhf_(accT) * T_W2[tid];
    float termA = tanhf_(accA) * A_W2[tid];
    termT = wave_reduce_sum(termT);
    termA = wave_reduce_sum(termA);
    if (lane == 0){ s_redT[w] = termT; s_redA[w] = termA; }
    __syncthreads();
    if (tid == 0){
      t_val[b] = s_redT[0] + s_redT[1] + s_redT[2] + s_redT[3] + T_b2[0];
      float v = s_redA[0] + s_redA[1] + s_redA[2] + s_redA[3] + A_b2[0];
      a_val[b] = 8.f * (sigmoidf_(fabsf(v)) - 0.5f);
    }
  }
}

// ---------------------------------------------------------------------------
// Kernel 2: MFMA LSTM, R9: 16-WAVE GATE-SPLIT. Diagnosis: step = ~2600 cyc
// vs ~700 issue+chain floor at 2 waves/SIMD (Occupancy 19.6%); R4 proved
// more waves/CU helps (43% occ) but 2-block co-residency fails on regalloc.
// This gets 4 waves/SIMD with ONE 1024-thread block (grid stays 256 = all
// CUs): waves 0-7 compute gates i,f; waves 8-15 compute g,o. Per-wave MFMA
// 24->12, per-thread trans 40->20, wf VGPR 96->48 (total ~110 <= 128 needed
// for 16 waves/CU). Cost: +1 barrier/step + 16B/thread LDS gate exchange;
// each thread finishes 2 of 4 h-components. Per-element fp op order is
// unchanged -> bit-identical numerics (absmax 0.00390625).
// ---------------------------------------------------------------------------
#define HROW 280   // shorts/row: h0(128)|h1(128)|pad(24)

__global__ __launch_bounds__(1024) void lstm_kernel(
    const short* __restrict__ bvec, const int* __restrict__ qid_len,
    const float* __restrict__ L_Wi, const float* __restrict__ L_Wh,
    const float* __restrict__ L_b,  const float* __restrict__ L_Wo,
    const float* __restrict__ L_bo, const float* __restrict__ t_val,
    const float* __restrict__ a_val, float* __restrict__ out)
{
  __shared__ __align__(16) short s_A[16*HROW];
  __shared__ __align__(16) float s_eIF[16][130][2];  // i,f for r=2,3 (pad row=130 breaks bank conflicts)
  __shared__ __align__(16) float s_eGO[16][130][2];  // g,o for r=0,1
  __shared__ int s_len[16];

  const int tid   = threadIdx.x;
  const int s0    = blockIdx.x * 16;
  const int w     = tid >> 6;          // 0..15
  const int lane  = tid & 63;
  const int l15   = lane & 15;         // student
  const int quad  = lane >> 4;
  const int ghalf = w >> 3;            // 0: gates i,f   1: gates g,o
  const int wsub  = w & 7;             // 16-col block within hidden 128

  // Weight fragments for this wave's 2 gates: col = gate*128 + wsub*16 + l15,
  // k = kt*32 + quad*8 + j. 12 frags = 48 VGPR.
  bf16x8 wf[2][6];
  f32x4  biasv4[2];
  #pragma unroll
  for (int gg = 0; gg < 2; ++gg){
    const int gate = ghalf*2 + gg;
    const int col  = gate*128 + wsub*16 + l15;
    #pragma unroll
    for (int r = 0; r < 4; ++r) biasv4[gg][r] = L_b[gate*128 + wsub*16 + quad*4 + r];
    #pragma unroll
    for (int kt = 0; kt < 6; ++kt){
      #pragma unroll
      for (int j = 0; j < 8; ++j){
        int k = kt*32 + quad*8 + j;
        float v = (k < D_) ? L_Wi[k*G4_ + col] : L_Wh[(k-D_)*G4_ + col];
        wf[gg][kt][j] = f2bf(v);
      }
    }
  }

  for (int p = tid; p < 16*HROW; p += 1024) s_A[p] = 0;
  if (tid < 16) s_len[tid] = qid_len[s0 + tid];
  __syncthreads();

  int maxlen = 0;
  #pragma unroll
  for (int i = 0; i < 16; ++i) maxlen = max(maxlen, s_len[i]);
  const int mylen = s_len[l15];
  float c_reg[2] = {0.f, 0.f};
  float h_reg[2] = {0.f, 0.f};

  // x fragments direct from global (bf16), double-buffered in registers.
  // Both gate-halves load the same x (L1-absorbed duplication).
  const short* gx = bvec + (size_t)(s0 + l15)*T_*D_ + quad*8;
  bf16x8 xA0 = *(const bf16x8*)(gx);
  bf16x8 xA1 = *(const bf16x8*)(gx + 32);
  bf16x8 xB0 = xA0, xB1 = xA1;
  if (1 < maxlen){ xB0 = *(const bf16x8*)(gx + D_); xB1 = *(const bf16x8*)(gx + D_ + 32); }

#define MF(Aop, Bop, Cop) __builtin_amdgcn_mfma_f32_16x16x32_bf16((Aop), (Bop), (Cop), 0, 0, 0)

#define LSTM_STEP(TI, XB, XC0, XC1) do {                                       \
    const int hb_ = (XB) ^ 1;                                                  \
    const bf16x8 ah0 = *(const bf16x8*)&s_A[l15*HROW + hb_*128 +  0 + quad*8]; \
    const bf16x8 ah1 = *(const bf16x8*)&s_A[l15*HROW + hb_*128 + 32 + quad*8]; \
    const bf16x8 ah2 = *(const bf16x8*)&s_A[l15*HROW + hb_*128 + 64 + quad*8]; \
    const bf16x8 ah3 = *(const bf16x8*)&s_A[l15*HROW + hb_*128 + 96 + quad*8]; \
    f32x4 a0_ = biasv4[0], a1_ = biasv4[1];                                    \
    a0_ = MF(wf[0][0], XC0, a0_); a1_ = MF(wf[1][0], XC0, a1_);                \
    a0_ = MF(wf[0][1], XC1, a0_); a1_ = MF(wf[1][1], XC1, a1_);                \
    if ((TI) + 2 < maxlen){                                                    \
      XC0 = *(const bf16x8*)(gx + ((TI)+2)*D_);                                \
      XC1 = *(const bf16x8*)(gx + ((TI)+2)*D_ + 32);                           \
    }                                                                          \
    a0_ = MF(wf[0][2], ah0, a0_); a1_ = MF(wf[1][2], ah0, a1_);                \
    a0_ = MF(wf[0][3], ah1, a0_); a1_ = MF(wf[1][3], ah1, a1_);                \
    a0_ = MF(wf[0][4], ah2, a0_); a1_ = MF(wf[1][4], ah2, a1_);                \
    a0_ = MF(wf[0][5], ah3, a0_); a1_ = MF(wf[1][5], ah3, a1_);                \
    /* gate exchange: i,f(r=2,3) -> eIF ; g,o(r=0,1) -> eGO */                 \
    if (ghalf == 0){                                                           \
      float4 snd; snd.x = a0_[2]; snd.y = a1_[2]; snd.z = a0_[3]; snd.w = a1_[3]; \
      *(float4*)&s_eIF[l15][wsub*16 + quad*4 + 2][0] = snd;                    \
    } else {                                                                   \
      float4 snd; snd.x = a0_[0]; snd.y = a1_[0]; snd.z = a0_[1]; snd.w = a1_[1]; \
      *(float4*)&s_eGO[l15][wsub*16 + quad*4][0] = snd;                        \
    }                                                                          \
    __syncthreads();                                                           \
    const bool upd_ = (TI) < mylen;                                            \
    if (ghalf == 0){                                                           \
      const float4 rcv = *(const float4*)&s_eGO[l15][wsub*16 + quad*4][0];     \
      _Pragma("unroll")                                                        \
      for (int k = 0; k < 2; ++k){                                             \
        float gi = a0_[k], gf = a1_[k];                                        \
        float gg_ = (k ? rcv.z : rcv.x), go = (k ? rcv.w : rcv.y);             \
        float c2 = sigmoidf_(gf)*c_reg[k] + sigmoidf_(gi)*tanhf_(gg_);         \
        float h2 = sigmoidf_(go)*tanhf_(c2);                                   \
        c_reg[k] = upd_ ? c2 : c_reg[k];                                       \
        h_reg[k] = upd_ ? h2 : h_reg[k];                                       \
      }                                                                        \
      unsigned hp_ = (unsigned)(unsigned short)f2bf(h_reg[0])                  \
                   | ((unsigned)(unsigned short)f2bf(h_reg[1]) << 16);         \
      *(unsigned*)&s_A[l15*HROW + (XB)*128 + wsub*16 + quad*4] = hp_;          \
    } else {                                                                   \
      const float4 rcv = *(const float4*)&s_eIF[l15][wsub*16 + quad*4 + 2][0]; \
      _Pragma("unroll")                                                        \
      for (int k = 0; k < 2; ++k){                                             \
        float gi = (k ? rcv.z : rcv.x), gf = (k ? rcv.w : rcv.y);              \
        float gg_ = a0_[2+k], go = a1_[2+k];                                   \
        float c2 = sigmoidf_(gf)*c_reg[k] + sigmoidf_(gi)*tanhf_(gg_);         \
        float h2 = sigmoidf_(go)*tanhf_(c2);                                   \
        c_reg[k] = upd_ ? c2 : c_reg[k];                                       \
        h_reg[k] = upd_ ? h2 : h_reg[k];                                       \
      }                                                                        \
      unsigned hp_ = (unsigned)(unsigned short)f2bf(h_reg[0])                  \
                   | ((unsigned)(unsigned short)f2bf(h_reg[1]) << 16);         \
      *(unsigned*)&s_A[l15*HROW + (XB)*128 + wsub*16 + quad*4 + 2] = hp_;      \
    }                                                                          \
    __syncthreads();                                                           \
  } while(0)

  int t = 0;
  for (; t + 1 < maxlen; t += 2){
    LSTM_STEP(t,   0, xA0, xA1);
    LSTM_STEP(t+1, 1, xB0, xB1);
  }
  if (t < maxlen) LSTM_STEP(t, 0, xA0, xA1);
#undef LSTM_STEP
#undef MF

  const int xbLast = (maxlen - 1) & 1;
  {
    const int s2 = w;   // one wave per student
    float h0 = bf2f(s_A[s2*HROW + xbLast*128 + lane]);
    float h1 = bf2f(s_A[s2*HROW + xbLast*128 + 64 + lane]);
    float part = h0*L_Wo[lane] + h1*L_Wo[64+lane];
    part = wave_reduce_sum(part);
    if (lane == 0){
      float bb = 8.f * (sigmoidf_(part + L_bo[0]) - 0.5f);
      out[s0+s2] = sigmoidf_(a_val[s0+s2] * (t_val[s0+s2] - bb));
    }
  }
}

// ---------------------------------------------------------------------------
extern "C" void kernel_launch(void* const* d_in, const int* in_sizes, int n_in,
                              void* d_out, int out_size, void* d_ws, size_t ws_size,
                              hipStream_t stream)
{
  (void)in_sizes; (void)n_in; (void)out_size; (void)ws_size;
  const int*   uididx    = (const int*)  d_in[0];
  const int*   kcodeidx  = (const int*)  d_in[1];
  const int*   kcode_len = (const int*)  d_in[2];
  const float* qidemb    = (const float*)d_in[3];
  const int*   qid_len   = (const int*)  d_in[4];
  const float* stuE      = (const float*)d_in[5];
  const float* knE       = (const float*)d_in[6];
  const float* T_W1      = (const float*)d_in[7];
  const float* T_b1      = (const float*)d_in[8];
  const float* T_W2      = (const float*)d_in[9];
  const float* T_b2      = (const float*)d_in[10];
  const float* A_W1      = (const float*)d_in[11];
  const float* A_b1      = (const float*)d_in[12];
  const float* A_W2      = (const float*)d_in[13];
  const float* A_b2      = (const float*)d_in[14];
  const float* L_Wi      = (const float*)d_in[15];
  const float* L_Wh      = (const float*)d_in[16];
  const float* L_b       = (const float*)d_in[17];
  const float* L_Wo      = (const float*)d_in[18];
  const float* L_bo      = (const float*)d_in[19];
  float* out = (float*)d_out;

  short* bvec  = (short*)d_ws;                       // B*T*D bf16 = 26.2 MB
  float* t_val = (float*)(bvec + (size_t)B_*T_*D_);  // B floats
  float* a_val = t_val + B_;                         // B floats

  hipLaunchKernelGGL(head_kernel, dim3(B_), dim3(256), 0, stream,
    uididx, kcodeidx, kcode_len, qidemb, qid_len, stuE, knE,
    T_W1, T_b1, T_W2, T_b2, A_W1, A_b1, A_W2, A_b2,
    bvec, t_val, a_val);

  hipLaunchKernelGGL(lstm_kernel, dim3(B_/16), dim3(1024), 0, stream,
    bvec, qid_len, L_Wi, L_Wh, L_b, L_Wo, L_bo, t_val, a_val, out);
}

// Round 10
// 240.635 us; speedup vs baseline: 1.0004x; 1.0004x over previous
//
#include <hip/hip_runtime.h>
#include <math.h>

#define B_  4096
#define T_  50
#define K_  32
#define D_  64
#define H_  256
#define HL_ 128
#define G4_ 512   // 4*HL

typedef __attribute__((ext_vector_type(8))) short bf16x8;
typedef __attribute__((ext_vector_type(4))) float f32x4;

__device__ __forceinline__ float fast_exp(float x){ return __expf(x); }
__device__ __forceinline__ float fast_rcp(float x){ return __builtin_amdgcn_rcpf(x); }
__device__ __forceinline__ float sigmoidf_(float x){ return fast_rcp(1.f + fast_exp(-x)); }
__device__ __forceinline__ float tanhf_(float x){ return 1.f - 2.f*fast_rcp(1.f + fast_exp(2.f*x)); }

__device__ __forceinline__ short f2bf(float f){
  union { float f; unsigned u; } v; v.f = f;
  unsigned r = v.u + 0x7FFFu + ((v.u >> 16) & 1u);   // round-to-nearest-even
  return (short)(r >> 16);
}
__device__ __forceinline__ float bf2f(short s){
  union { unsigned u; float f; } v; v.u = ((unsigned)(unsigned short)s) << 16;
  return v.f;
}

__device__ __forceinline__ float wave_reduce_sum(float v){
  #pragma unroll
  for (int off = 32; off; off >>= 1) v += __shfl_xor(v, off);
  return v;
}

// ---------------------------------------------------------------------------
// Kernel 1: per-student head — verified R0-R3 baseline, unchanged.
// ---------------------------------------------------------------------------
#define KROW 72
#define PROW 40

__global__ __launch_bounds__(256) void head_kernel(
    const int* __restrict__ uididx, const int* __restrict__ kcodeidx,
    const int* __restrict__ kcode_len, const float* __restrict__ qidemb,
    const int* __restrict__ qid_len, const float* __restrict__ stuE,
    const float* __restrict__ knE,
    const float* __restrict__ T_W1, const float* __restrict__ T_b1,
    const float* __restrict__ T_W2, const float* __restrict__ T_b2,
    const float* __restrict__ A_W1, const float* __restrict__ A_b1,
    const float* __restrict__ A_W2, const float* __restrict__ A_b2,
    short* __restrict__ bvec, float* __restrict__ t_val, float* __restrict__ a_val)
{
  __shared__ __align__(16) short s_kemb[K_*KROW];
  __shared__ __align__(16) short s_kembT[D_*PROW];
  __shared__ __align__(16) short s_p[64*PROW];
  __shared__ float s_stu[D_];
  __shared__ float s_mast[K_];
  __shared__ float s_kmf[K_];
  __shared__ float s_mvec[D_];
  __shared__ float s_avec[D_];
  __shared__ float s_redT[4];
  __shared__ float s_redA[4];

  const int b    = blockIdx.x;
  const int tid  = threadIdx.x;
  const int lane = tid & 63;
  const int w    = tid >> 6;
  const int l15  = lane & 15;
  const int quad = lane >> 4;
  const int klen = kcode_len[b];
  const int qlen = qid_len[b];

  if (tid < D_) s_stu[tid] = stuE[uididx[b]*D_ + tid];
  #pragma unroll
  for (int i = tid; i < 512; i += 256){
    int k = i >> 4, f4 = i & 15;
    const float4 v = *(const float4*)&knE[(size_t)kcodeidx[b*K_ + k]*D_ + f4*4];
    short4 b4; b4.x = f2bf(v.x); b4.y = f2bf(v.y); b4.z = f2bf(v.z); b4.w = f2bf(v.w);
    *(short4*)&s_kemb[k*KROW + f4*4] = b4;
    int d = f4*4;
    s_kembT[(d+0)*PROW + k] = b4.x;
    s_kembT[(d+1)*PROW + k] = b4.y;
    s_kembT[(d+2)*PROW + k] = b4.z;
    s_kembT[(d+3)*PROW + k] = b4.w;
  }
  __syncthreads();

  // mastery: 8 lanes per k, bank-rotated
  {
    int k = tid >> 3, l8 = tid & 7;
    float s = 0.f;
    #pragma unroll
    for (int j = 0; j < 8; ++j){
      int d = l8 + 8*((j + k) & 7);
      s += s_stu[d] * bf2f(s_kemb[k*KROW + d]);
    }
    s += __shfl_xor(s, 1); s += __shfl_xor(s, 2); s += __shfl_xor(s, 4);
    if (l8 == 0){
      float valid = (k < klen) ? 1.f : 0.f;
      s_mast[k] = valid * sigmoidf_(s * 0.2f);
      s_kmf[k]  = valid;
    }
  }
  __syncthreads();

  if (tid < D_){
    float mv = 0.f, av = 0.f;
    #pragma unroll 4
    for (int k = 0; k < K_; ++k){
      float e = bf2f(s_kemb[k*KROW + tid]);
      mv += s_mast[k] * e;
      av += s_kmf[k]  * e;
    }
    s_mvec[tid] = mv; s_avec[tid] = av;
  }
  __syncthreads();

  // ---- attention via MFMA; q A-frags straight from global ----
  {
    const int qrow = w*16 + l15;
    bf16x8 aq[2];
    #pragma unroll
    for (int kt = 0; kt < 2; ++kt){
      if (qrow < qlen){
        const float4 v0 = *(const float4*)&qidemb[((size_t)b*T_ + qrow)*D_ + kt*32 + quad*8];
        const float4 v1 = *(const float4*)&qidemb[((size_t)b*T_ + qrow)*D_ + kt*32 + quad*8 + 4];
        aq[kt][0]=f2bf(v0.x); aq[kt][1]=f2bf(v0.y); aq[kt][2]=f2bf(v0.z); aq[kt][3]=f2bf(v0.w);
        aq[kt][4]=f2bf(v1.x); aq[kt][5]=f2bf(v1.y); aq[kt][6]=f2bf(v1.z); aq[kt][7]=f2bf(v1.w);
      } else {
        aq[kt][0]=0; aq[kt][1]=0; aq[kt][2]=0; aq[kt][3]=0;
        aq[kt][4]=0; aq[kt][5]=0; aq[kt][6]=0; aq[kt][7]=0;
      }
    }
    f32x4 zero = {0.f, 0.f, 0.f, 0.f};
    f32x4 accs[2] = {zero, zero};
    #pragma unroll
    for (int kt = 0; kt < 2; ++kt){
      #pragma unroll
      for (int nt = 0; nt < 2; ++nt){
        bf16x8 bk = *(const bf16x8*)&s_kemb[(nt*16 + l15)*KROW + kt*32 + quad*8];
        accs[nt] = __builtin_amdgcn_mfma_f32_16x16x32_bf16(aq[kt], bk, accs[nt], 0, 0, 0);
      }
    }
    #pragma unroll
    for (int r = 0; r < 4; ++r){
      float v0 = (l15      < klen) ? accs[0][r]*0.15f : -1e9f;
      float v1 = (l15 + 16 < klen) ? accs[1][r]*0.15f : -1e9f;
      float mx = fmaxf(v0, v1);
      #pragma unroll
      for (int off = 1; off < 16; off <<= 1) mx = fmaxf(mx, __shfl_xor(mx, off));
      float e0 = fast_exp(v0 - mx), e1 = fast_exp(v1 - mx);
      float sm = e0 + e1;
      #pragma unroll
      for (int off = 1; off < 16; off <<= 1) sm += __shfl_xor(sm, off);
      float inv = fast_rcp(sm);
      int row = w*16 + quad*4 + r;
      s_p[row*PROW + l15]      = f2bf(e0 * inv);
      s_p[row*PROW + 16 + l15] = f2bf(e1 * inv);
    }
    bf16x8 ap = *(const bf16x8*)&s_p[(w*16 + l15)*PROW + quad*8];
    #pragma unroll
    for (int nt = 0; nt < 4; ++nt){
      bf16x8 bv = *(const bf16x8*)&s_kembT[(nt*16 + l15)*PROW + quad*8];
      f32x4 acco = __builtin_amdgcn_mfma_f32_16x16x32_bf16(ap, bv, zero, 0, 0, 0);
      #pragma unroll
      for (int r = 0; r < 4; ++r){
        int t = w*16 + quad*4 + r;
        if (t < qlen) bvec[((size_t)b*T_ + t)*D_ + nt*16 + l15] = f2bf(acco[r]);
      }
    }
  }

  // ---- both DNNs interleaved (verified baseline form) ----
  {
    float accT = T_b1[tid];
    float accA = A_b1[tid];
    #pragma unroll 4
    for (int d = 0; d < D_; ++d){
      float mv = s_mvec[d], av = s_avec[d];
      accT += mv * T_W1[d*H_ + tid];
      accA += av * A_W1[d*H_ + tid];
    }
    float termT = tanhf_(accT) * T_W2[tid];
    float termA = tanhf_(accA) * A_W2[tid];
    termT = wave_reduce_sum(termT);
    termA = wave_reduce_sum(termA);
    if (lane == 0){ s_redT[w] = termT; s_redA[w] = termA; }
    __syncthreads();
    if (tid == 0){
      t_val[b] = s_redT[0] + s_redT[1] + s_redT[2] + s_redT[3] + T_b2[0];
      float v = s_redA[0] + s_redA[1] + s_redA[2] + s_redA[3] + A_b2[0];
      a_val[b] = 8.f * (sigmoidf_(fabsf(v)) - 0.5f);
    }
  }
}

// ---------------------------------------------------------------------------
// Kernel 2: MFMA LSTM, R10 = R9 16-wave gate-split with the CORRECT regalloc
// constraint. R9 post-mortem: __launch_bounds__(1024) without min-waves let
// the compiler target 32 waves/CU -> 64-VGPR cap -> wf spilled to scratch
// (WRITE 16B->19.5MB, FETCH +8MB, 87.6us despite 41% occupancy — mechanism
// PROVEN, regalloc wrong, same failure shape as R4). Fix:
// __launch_bounds__(1024, 4): 4 waves/EU x (1024/64=16 waves) = 1 block/CU
// -> 128-VGPR cap; natural allocation ~110 (48 wf + af + acc + x-dbuf).
// Decision rule: if lstm >= 66us spill-free at ~40% occupancy, the step is
// pure intra-step dependency-chain latency -> structure converged.
// ---------------------------------------------------------------------------
#define HROW 280   // shorts/row: h0(128)|h1(128)|pad(24)

__global__ __launch_bounds__(1024, 4) void lstm_kernel(
    const short* __restrict__ bvec, const int* __restrict__ qid_len,
    const float* __restrict__ L_Wi, const float* __restrict__ L_Wh,
    const float* __restrict__ L_b,  const float* __restrict__ L_Wo,
    const float* __restrict__ L_bo, const float* __restrict__ t_val,
    const float* __restrict__ a_val, float* __restrict__ out)
{
  __shared__ __align__(16) short s_A[16*HROW];
  __shared__ __align__(16) float s_eIF[16][130][2];  // i,f for r=2,3
  __shared__ __align__(16) float s_eGO[16][130][2];  // g,o for r=0,1
  __shared__ int s_len[16];

  const int tid   = threadIdx.x;
  const int s0    = blockIdx.x * 16;
  const int w     = tid >> 6;          // 0..15
  const int lane  = tid & 63;
  const int l15   = lane & 15;         // student
  const int quad  = lane >> 4;
  const int ghalf = w >> 3;            // 0: gates i,f   1: gates g,o
  const int wsub  = w & 7;             // 16-col block within hidden 128

  // Weight fragments for this wave's 2 gates: col = gate*128 + wsub*16 + l15,
  // k = kt*32 + quad*8 + j. 12 frags = 48 VGPR.
  bf16x8 wf[2][6];
  f32x4  biasv4[2];
  #pragma unroll
  for (int gg = 0; gg < 2; ++gg){
    const int gate = ghalf*2 + gg;
    const int col  = gate*128 + wsub*16 + l15;
    #pragma unroll
    for (int r = 0; r < 4; ++r) biasv4[gg][r] = L_b[gate*128 + wsub*16 + quad*4 + r];
    #pragma unroll
    for (int kt = 0; kt < 6; ++kt){
      #pragma unroll
      for (int j = 0; j < 8; ++j){
        int k = kt*32 + quad*8 + j;
        float v = (k < D_) ? L_Wi[k*G4_ + col] : L_Wh[(k-D_)*G4_ + col];
        wf[gg][kt][j] = f2bf(v);
      }
    }
  }

  for (int p = tid; p < 16*HROW; p += 1024) s_A[p] = 0;
  if (tid < 16) s_len[tid] = qid_len[s0 + tid];
  __syncthreads();

  int maxlen = 0;
  #pragma unroll
  for (int i = 0; i < 16; ++i) maxlen = max(maxlen, s_len[i]);
  const int mylen = s_len[l15];
  float c_reg[2] = {0.f, 0.f};
  float h_reg[2] = {0.f, 0.f};

  // x fragments direct from global (bf16), double-buffered in registers.
  // Both gate-halves load the same x (L1-absorbed duplication).
  const short* gx = bvec + (size_t)(s0 + l15)*T_*D_ + quad*8;
  bf16x8 xA0 = *(const bf16x8*)(gx);
  bf16x8 xA1 = *(const bf16x8*)(gx + 32);
  bf16x8 xB0 = xA0, xB1 = xA1;
  if (1 < maxlen){ xB0 = *(const bf16x8*)(gx + D_); xB1 = *(const bf16x8*)(gx + D_ + 32); }

#define MF(Aop, Bop, Cop) __builtin_amdgcn_mfma_f32_16x16x32_bf16((Aop), (Bop), (Cop), 0, 0, 0)

#define LSTM_STEP(TI, XB, XC0, XC1) do {                                       \
    const int hb_ = (XB) ^ 1;                                                  \
    const bf16x8 ah0 = *(const bf16x8*)&s_A[l15*HROW + hb_*128 +  0 + quad*8]; \
    const bf16x8 ah1 = *(const bf16x8*)&s_A[l15*HROW + hb_*128 + 32 + quad*8]; \
    const bf16x8 ah2 = *(const bf16x8*)&s_A[l15*HROW + hb_*128 + 64 + quad*8]; \
    const bf16x8 ah3 = *(const bf16x8*)&s_A[l15*HROW + hb_*128 + 96 + quad*8]; \
    f32x4 a0_ = biasv4[0], a1_ = biasv4[1];                                    \
    a0_ = MF(wf[0][0], XC0, a0_); a1_ = MF(wf[1][0], XC0, a1_);                \
    a0_ = MF(wf[0][1], XC1, a0_); a1_ = MF(wf[1][1], XC1, a1_);                \
    if ((TI) + 2 < maxlen){                                                    \
      XC0 = *(const bf16x8*)(gx + ((TI)+2)*D_);                                \
      XC1 = *(const bf16x8*)(gx + ((TI)+2)*D_ + 32);                           \
    }                                                                          \
    a0_ = MF(wf[0][2], ah0, a0_); a1_ = MF(wf[1][2], ah0, a1_);                \
    a0_ = MF(wf[0][3], ah1, a0_); a1_ = MF(wf[1][3], ah1, a1_);                \
    a0_ = MF(wf[0][4], ah2, a0_); a1_ = MF(wf[1][4], ah2, a1_);                \
    a0_ = MF(wf[0][5], ah3, a0_); a1_ = MF(wf[1][5], ah3, a1_);                \
    /* gate exchange: i,f(r=2,3) -> eIF ; g,o(r=0,1) -> eGO */                 \
    if (ghalf == 0){                                                           \
      float4 snd; snd.x = a0_[2]; snd.y = a1_[2]; snd.z = a0_[3]; snd.w = a1_[3]; \
      *(float4*)&s_eIF[l15][wsub*16 + quad*4 + 2][0] = snd;                    \
    } else {                                                                   \
      float4 snd; snd.x = a0_[0]; snd.y = a1_[0]; snd.z = a0_[1]; snd.w = a1_[1]; \
      *(float4*)&s_eGO[l15][wsub*16 + quad*4][0] = snd;                        \
    }                                                                          \
    __syncthreads();                                                           \
    const bool upd_ = (TI) < mylen;                                            \
    if (ghalf == 0){                                                           \
      const float4 rcv = *(const float4*)&s_eGO[l15][wsub*16 + quad*4][0];     \
      _Pragma("unroll")                                                        \
      for (int k = 0; k < 2; ++k){                                             \
        float gi = a0_[k], gf = a1_[k];                                        \
        float gg_ = (k ? rcv.z : rcv.x), go = (k ? rcv.w : rcv.y);             \
        float c2 = sigmoidf_(gf)*c_reg[k] + sigmoidf_(gi)*tanhf_(gg_);         \
        float h2 = sigmoidf_(go)*tanhf_(c2);                                   \
        c_reg[k] = upd_ ? c2 : c_reg[k];                                       \
        h_reg[k] = upd_ ? h2 : h_reg[k];                                       \
      }                                                                        \
      unsigned hp_ = (unsigned)(unsigned short)f2bf(h_reg[0])                  \
                   | ((unsigned)(unsigned short)f2bf(h_reg[1]) << 16);         \
      *(unsigned*)&s_A[l15*HROW + (XB)*128 + wsub*16 + quad*4] = hp_;          \
    } else {                                                                   \
      const float4 rcv = *(const float4*)&s_eIF[l15][wsub*16 + quad*4 + 2][0]; \
      _Pragma("unroll")                                                        \
      for (int k = 0; k < 2; ++k){                                             \
        float gi = (k ? rcv.z : rcv.x), gf = (k ? rcv.w : rcv.y);              \
        float gg_ = a0_[2+k], go = a1_[2+k];                                   \
        float c2 = sigmoidf_(gf)*c_reg[k] + sigmoidf_(gi)*tanhf_(gg_);         \
        float h2 = sigmoidf_(go)*tanhf_(c2);                                   \
        c_reg[k] = upd_ ? c2 : c_reg[k];                                       \
        h_reg[k] = upd_ ? h2 : h_reg[k];                                       \
      }                                                                        \
      unsigned hp_ = (unsigned)(unsigned short)f2bf(h_reg[0])                  \
                   | ((unsigned)(unsigned short)f2bf(h_reg[1]) << 16);         \
      *(unsigned*)&s_A[l15*HROW + (XB)*128 + wsub*16 + quad*4 + 2] = hp_;      \
    }                                                                          \
    __syncthreads();                                                           \
  } while(0)

  int t = 0;
  for (; t + 1 < maxlen; t += 2){
    LSTM_STEP(t,   0, xA0, xA1);
    LSTM_STEP(t+1, 1, xB0, xB1);
  }
  if (t < maxlen) LSTM_STEP(t, 0, xA0, xA1);
#undef LSTM_STEP
#undef MF

  const int xbLast = (maxlen - 1) & 1;
  {
    const int s2 = w;   // one wave per student
    float h0 = bf2f(s_A[s2*HROW + xbLast*128 + lane]);
    float h1 = bf2f(s_A[s2*HROW + xbLast*128 + 64 + lane]);
    float part = h0*L_Wo[lane] + h1*L_Wo[64+lane];
    part = wave_reduce_sum(part);
    if (lane == 0){
      float bb = 8.f * (sigmoidf_(part + L_bo[0]) - 0.5f);
      out[s0+s2] = sigmoidf_(a_val[s0+s2] * (t_val[s0+s2] - bb));
    }
  }
}

// ---------------------------------------------------------------------------
extern "C" void kernel_launch(void* const* d_in, const int* in_sizes, int n_in,
                              void* d_out, int out_size, void* d_ws, size_t ws_size,
                              hipStream_t stream)
{
  (void)in_sizes; (void)n_in; (void)out_size; (void)ws_size;
  const int*   uididx    = (const int*)  d_in[0];
  const int*   kcodeidx  = (const int*)  d_in[1];
  const int*   kcode_len = (const int*)  d_in[2];
  const float* qidemb    = (const float*)d_in[3];
  const int*   qid_len   = (const int*)  d_in[4];
  const float* stuE      = (const float*)d_in[5];
  const float* knE       = (const float*)d_in[6];
  const float* T_W1      = (const float*)d_in[7];
  const float* T_b1      = (const float*)d_in[8];
  const float* T_W2      = (const float*)d_in[9];
  const float* T_b2      = (const float*)d_in[10];
  const float* A_W1      = (const float*)d_in[11];
  const float* A_b1      = (const float*)d_in[12];
  const float* A_W2      = (const float*)d_in[13];
  const float* A_b2      = (const float*)d_in[14];
  const float* L_Wi      = (const float*)d_in[15];
  const float* L_Wh      = (const float*)d_in[16];
  const float* L_b       = (const float*)d_in[17];
  const float* L_Wo      = (const float*)d_in[18];
  const float* L_bo      = (const float*)d_in[19];
  float* out = (float*)d_out;

  short* bvec  = (short*)d_ws;                       // B*T*D bf16 = 26.2 MB
  float* t_val = (float*)(bvec + (size_t)B_*T_*D_);  // B floats
  float* a_val = t_val + B_;                         // B floats

  hipLaunchKernelGGL(head_kernel, dim3(B_), dim3(256), 0, stream,
    uididx, kcodeidx, kcode_len, qidemb, qid_len, stuE, knE,
    T_W1, T_b1, T_W2, T_b2, A_W1, A_b1, A_W2, A_b2,
    bvec, t_val, a_val);

  hipLaunchKernelGGL(lstm_kernel, dim3(B_/16), dim3(1024), 0, stream,
    bvec, qid_len, L_Wi, L_Wh, L_b, L_Wo, L_bo, t_val, a_val, out);
}